// Round 1
// baseline (4321.736 us; speedup 1.0000x reference)
//
#include <hip/hip_runtime.h>
#include <hip/hip_bf16.h>

// GIN 2-layer: per layer, agg = scatter_add(h[src] -> dst), then
// out = [relu]( relu((agg+h) @ Wa + ba) @ Wb + bb ).
// f32 throughout (reference is f32; threshold is 2% of ref absmax).

#define HIDC 128

// ---------------- scatter-add aggregation (atomic f32) ----------------
template<int C>
__global__ __launch_bounds__(256) void scatter_add_k(
    const float* __restrict__ hsrc, const int* __restrict__ src,
    const int* __restrict__ dst, float* __restrict__ agg, int n_edges)
{
    constexpr int Q = C / 4;                 // float4 chunks per edge
    int idx = blockIdx.x * 256 + threadIdx.x;
    int e = idx / Q;
    if (e >= n_edges) return;
    int q = idx - e * Q;
    int s = src[e], d = dst[e];
    const float4 v = *reinterpret_cast<const float4*>(&hsrc[(size_t)s * C + q * 4]);
    float* p = &agg[(size_t)d * C + q * 4];
    unsafeAtomicAdd(p + 0, v.x);
    unsafeAtomicAdd(p + 1, v.y);
    unsafeAtomicAdd(p + 2, v.z);
    unsafeAtomicAdd(p + 3, v.w);
}

// ---------------- fused 2-GEMM MLP for one GIN layer ----------------
// Block: 256 threads, 64-row tile. GEMM1: (64 x K1)@(K1 x 128), relu+bias -> sMid.
// GEMM2: (64 x 128)@(128 x N2) + bias [+relu] -> out.
// LDS: sA 8KB + sW 16KB + sMid 32KB = 56KB -> 2 blocks/CU.
template<int K1, int N2, bool FINAL_RELU>
__global__ __launch_bounds__(256) void fused_mlp(
    const float* __restrict__ agg, const float* __restrict__ xin,
    const float* __restrict__ Wa, const float* __restrict__ ba,
    const float* __restrict__ Wb, const float* __restrict__ bb,
    float* __restrict__ out, int n_nodes)
{
    __shared__ __align__(16) float sA[32][64];       // A chunk, k-major
    __shared__ __align__(16) float sW[32][HIDC];     // weight chunk (reused Wa/Wb)
    __shared__ __align__(16) float sMid[HIDC][64];   // GEMM1 output, k-major

    const int tid = threadIdx.x;
    const int tx = tid & 15;        // 16 col groups
    const int ty = tid >> 4;        // 16 row groups
    const int r0 = ty * 4;
    const int c0 = tx * 8;          // GEMM1: 8 cols/thread (N1=128)
    const int rowBlock = blockIdx.x * 64;

    // ---------------- GEMM1 ----------------
    float acc[4][8];
    #pragma unroll
    for (int i = 0; i < 4; ++i)
        #pragma unroll
        for (int j = 0; j < 8; ++j) acc[i][j] = 0.f;

    for (int kk = 0; kk < K1; kk += 32) {
        // load A chunk (64 rows x 32 k), A = agg + xin
        #pragma unroll
        for (int i = 0; i < 2; ++i) {
            int f = tid + i * 256;          // 0..511 float4 slots
            int row = f >> 3, c4 = f & 7;
            int grow = rowBlock + row;
            float4 v = make_float4(0.f, 0.f, 0.f, 0.f);
            if (grow < n_nodes) {
                size_t off = (size_t)grow * K1 + kk + c4 * 4;
                float4 a = *reinterpret_cast<const float4*>(agg + off);
                float4 b = *reinterpret_cast<const float4*>(xin + off);
                v.x = a.x + b.x; v.y = a.y + b.y; v.z = a.z + b.z; v.w = a.w + b.w;
            }
            sA[c4 * 4 + 0][row] = v.x;
            sA[c4 * 4 + 1][row] = v.y;
            sA[c4 * 4 + 2][row] = v.z;
            sA[c4 * 4 + 3][row] = v.w;
        }
        // load Wa chunk (32 x 128)
        #pragma unroll
        for (int i = 0; i < 4; ++i) {
            int f = tid + i * 256;          // 0..1023
            int r = f >> 5, c4 = f & 31;
            *reinterpret_cast<float4*>(&sW[r][c4 * 4]) =
                *reinterpret_cast<const float4*>(&Wa[(size_t)(kk + r) * HIDC + c4 * 4]);
        }
        __syncthreads();
        #pragma unroll
        for (int k = 0; k < 32; ++k) {
            float4 a  = *reinterpret_cast<const float4*>(&sA[k][r0]);
            float4 b0 = *reinterpret_cast<const float4*>(&sW[k][c0]);
            float4 b1 = *reinterpret_cast<const float4*>(&sW[k][c0 + 4]);
            float av[4] = {a.x, a.y, a.z, a.w};
            float bv[8] = {b0.x, b0.y, b0.z, b0.w, b1.x, b1.y, b1.z, b1.w};
            #pragma unroll
            for (int i = 0; i < 4; ++i)
                #pragma unroll
                for (int j = 0; j < 8; ++j)
                    acc[i][j] = fmaf(av[i], bv[j], acc[i][j]);
        }
        __syncthreads();
    }
    // epilogue 1: bias + relu, transpose into sMid (k-major)
    #pragma unroll
    for (int j = 0; j < 8; ++j) {
        float bj = ba[c0 + j];
        #pragma unroll
        for (int i = 0; i < 4; ++i) {
            float v = fmaxf(acc[i][j] + bj, 0.f);
            sMid[c0 + j][r0 + i] = v;
        }
    }

    // ---------------- GEMM2 ----------------
    constexpr int JW = (N2 == 128) ? 8 : 4;
    const int c02 = tx * JW;
    float acc2[4][JW];
    #pragma unroll
    for (int i = 0; i < 4; ++i)
        #pragma unroll
        for (int j = 0; j < JW; ++j) acc2[i][j] = 0.f;

    for (int kk = 0; kk < HIDC; kk += 32) {
        constexpr int NF4 = 32 * N2 / 4;        // float4 count per chunk
        #pragma unroll
        for (int i = 0; i < NF4 / 256; ++i) {
            int f = tid + i * 256;
            int r = f / (N2 / 4), c4 = f % (N2 / 4);
            *reinterpret_cast<float4*>(&sW[r][c4 * 4]) =
                *reinterpret_cast<const float4*>(&Wb[(size_t)(kk + r) * N2 + c4 * 4]);
        }
        __syncthreads();
        #pragma unroll
        for (int k = 0; k < 32; ++k) {
            float4 a = *reinterpret_cast<const float4*>(&sMid[kk + k][r0]);
            float av[4] = {a.x, a.y, a.z, a.w};
            float bv[JW];
            float4 b0 = *reinterpret_cast<const float4*>(&sW[k][c02]);
            bv[0] = b0.x; bv[1] = b0.y; bv[2] = b0.z; bv[3] = b0.w;
            if constexpr (JW == 8) {
                float4 b1 = *reinterpret_cast<const float4*>(&sW[k][c02 + 4]);
                bv[4] = b1.x; bv[5] = b1.y; bv[6] = b1.z; bv[7] = b1.w;
            }
            #pragma unroll
            for (int i = 0; i < 4; ++i)
                #pragma unroll
                for (int j = 0; j < JW; ++j)
                    acc2[i][j] = fmaf(av[i], bv[j], acc2[i][j]);
        }
        __syncthreads();
    }
    // epilogue 2: bias [+relu], store
    #pragma unroll
    for (int i = 0; i < 4; ++i) {
        int grow = rowBlock + r0 + i;
        if (grow < n_nodes) {
            #pragma unroll
            for (int j4 = 0; j4 < JW / 4; ++j4) {
                float4 v;
                v.x = acc2[i][j4 * 4 + 0] + bb[c02 + j4 * 4 + 0];
                v.y = acc2[i][j4 * 4 + 1] + bb[c02 + j4 * 4 + 1];
                v.z = acc2[i][j4 * 4 + 2] + bb[c02 + j4 * 4 + 2];
                v.w = acc2[i][j4 * 4 + 3] + bb[c02 + j4 * 4 + 3];
                if (FINAL_RELU) {
                    v.x = fmaxf(v.x, 0.f); v.y = fmaxf(v.y, 0.f);
                    v.z = fmaxf(v.z, 0.f); v.w = fmaxf(v.w, 0.f);
                }
                *reinterpret_cast<float4*>(&out[(size_t)grow * N2 + c02 + j4 * 4]) = v;
            }
        }
    }
}

extern "C" void kernel_launch(void* const* d_in, const int* in_sizes, int n_in,
                              void* d_out, int out_size, void* d_ws, size_t ws_size,
                              hipStream_t stream)
{
    const float* x   = (const float*)d_in[0];
    const int*   ei  = (const int*)d_in[1];
    const float* W1a = (const float*)d_in[2];
    const float* b1a = (const float*)d_in[3];
    const float* W1b = (const float*)d_in[4];
    const float* b1b = (const float*)d_in[5];
    const float* W2a = (const float*)d_in[6];
    const float* b2a = (const float*)d_in[7];
    const float* W2b = (const float*)d_in[8];
    const float* b2b = (const float*)d_in[9];

    const int n_nodes = in_sizes[0] / 64;
    const int n_edges = in_sizes[1] / 2;
    const int* src = ei;
    const int* dst = ei + n_edges;

    // workspace layout: [agg: n_nodes*128 f32][h: n_nodes*128 f32] = 102.4 MB
    char* ws = (char*)d_ws;
    float* agg = (float*)ws;
    float* h   = (float*)(ws + (size_t)n_nodes * HIDC * sizeof(float));
    float* out = (float*)d_out;

    const int mlp_grid = (n_nodes + 63) / 64;

    // ---- layer 1 ----
    hipMemsetAsync(agg, 0, (size_t)n_nodes * 64 * sizeof(float), stream);
    {
        int total = n_edges * 16;       // 16 float4 chunks per edge (C=64)
        scatter_add_k<64><<<(total + 255) / 256, 256, 0, stream>>>(x, src, dst, agg, n_edges);
    }
    fused_mlp<64, 128, true><<<mlp_grid, 256, 0, stream>>>(
        agg, x, W1a, b1a, W1b, b1b, h, n_nodes);

    // ---- layer 2 ----
    hipMemsetAsync(agg, 0, (size_t)n_nodes * HIDC * sizeof(float), stream);
    {
        int total = n_edges * 32;       // 32 float4 chunks per edge (C=128)
        scatter_add_k<128><<<(total + 255) / 256, 256, 0, stream>>>(h, src, dst, agg, n_edges);
    }
    fused_mlp<128, 64, false><<<mlp_grid, 256, 0, stream>>>(
        agg, h, W2a, b2a, W2b, b2b, out, n_nodes);
}

// Round 2
// 644.353 us; speedup vs baseline: 6.7071x; 6.7071x over previous
//
#include <hip/hip_runtime.h>
#include <hip/hip_bf16.h>

// GIN 2-layer. Aggregation via on-device CSR build + gather (no f32 atomics).
// Per layer: agg[i] = sum_{e:dst=i} h[src[e]]; out = [relu](relu((agg+h)Wa+ba)Wb+bb).

#define HIDC 128

__device__ inline void add4(float4& a, const float4 b) {
    a.x += b.x; a.y += b.y; a.z += b.z; a.w += b.w;
}

// ---------------- CSR build ----------------
__global__ __launch_bounds__(256) void hist_k(
    const int* __restrict__ dst, int* __restrict__ cnt, int n_edges)
{
    int e = blockIdx.x * 256 + threadIdx.x;
    if (e < n_edges) atomicAdd(&cnt[dst[e]], 1);
}

// block-local exclusive scan over 2048 elements (256 thr x 8)
__global__ __launch_bounds__(256) void scan_block_k(
    const int* __restrict__ cnt, int* __restrict__ offs, int* __restrict__ bsum, int n)
{
    __shared__ int s[256];
    const int tid = threadIdx.x;
    const int base = blockIdx.x * 2048 + tid * 8;
    int v[8]; int tsum = 0;
    #pragma unroll
    for (int j = 0; j < 8; ++j) {
        int idx = base + j;
        v[j] = (idx < n) ? cnt[idx] : 0;
        tsum += v[j];
    }
    s[tid] = tsum; __syncthreads();
    #pragma unroll
    for (int d = 1; d < 256; d <<= 1) {
        int t = (tid >= d) ? s[tid - d] : 0;
        __syncthreads();
        s[tid] += t;
        __syncthreads();
    }
    int run = s[tid] - tsum;      // exclusive prefix within block
    #pragma unroll
    for (int j = 0; j < 8; ++j) {
        int idx = base + j;
        if (idx < n) offs[idx] = run;
        run += v[j];
    }
    if (tid == 255) bsum[blockIdx.x] = s[255];
}

__global__ __launch_bounds__(256) void scan_bsum_k(int* __restrict__ bsum, int nb)
{
    __shared__ int s[256];
    const int tid = threadIdx.x;
    int v = (tid < nb) ? bsum[tid] : 0;
    s[tid] = v; __syncthreads();
    #pragma unroll
    for (int d = 1; d < 256; d <<= 1) {
        int t = (tid >= d) ? s[tid - d] : 0;
        __syncthreads();
        s[tid] += t;
        __syncthreads();
    }
    if (tid < nb) bsum[tid] = s[tid] - v;   // exclusive block offsets
}

__global__ __launch_bounds__(256) void scan_add_k(
    int* __restrict__ offs, int* __restrict__ cur, const int* __restrict__ bsum, int n)
{
    const int b = bsum[blockIdx.x];
    const int base = blockIdx.x * 2048 + threadIdx.x * 8;
    #pragma unroll
    for (int j = 0; j < 8; ++j) {
        int idx = base + j;
        if (idx < n) { int o = offs[idx] + b; offs[idx] = o; cur[idx] = o; }
    }
}

__global__ __launch_bounds__(256) void fill_k(
    const int* __restrict__ src, const int* __restrict__ dst,
    int* __restrict__ cur, int* __restrict__ eidx, int n_edges)
{
    int e = blockIdx.x * 256 + threadIdx.x;
    if (e < n_edges) {
        int p = atomicAdd(&cur[dst[e]], 1);
        eidx[p] = src[e];
    }
}

// ---------------- gather aggregation ----------------
// TPN = C/8 threads per node; each thread owns 8 contiguous floats (2x float4).
template<int C>
__global__ __launch_bounds__(256) void gather_agg_k(
    const float* __restrict__ h, const int* __restrict__ offs,
    const int* __restrict__ cnt, const int* __restrict__ eidx,
    float* __restrict__ agg, int n_nodes)
{
    constexpr int TPN = C / 8;
    constexpr int NPB = 256 / TPN;
    const int node = blockIdx.x * NPB + threadIdx.x / TPN;
    const int lane = threadIdx.x % TPN;
    if (node >= n_nodes) return;
    const int beg = offs[node];
    const int end = beg + cnt[node];
    const size_t coff = (size_t)lane * 8;

    float4 a0 = {0,0,0,0}, a1 = {0,0,0,0}, a2 = {0,0,0,0}, a3 = {0,0,0,0};
    int p = beg;
    for (; p + 2 <= end; p += 2) {
        int s0 = eidx[p], s1 = eidx[p + 1];
        const float4* q0 = reinterpret_cast<const float4*>(h + (size_t)s0 * C + coff);
        const float4* q1 = reinterpret_cast<const float4*>(h + (size_t)s1 * C + coff);
        float4 u0 = q0[0], u1 = q0[1], w0 = q1[0], w1 = q1[1];
        add4(a0, u0); add4(a1, u1); add4(a2, w0); add4(a3, w1);
    }
    if (p < end) {
        int s0 = eidx[p];
        const float4* q0 = reinterpret_cast<const float4*>(h + (size_t)s0 * C + coff);
        float4 u0 = q0[0], u1 = q0[1];
        add4(a0, u0); add4(a1, u1);
    }
    add4(a0, a2); add4(a1, a3);
    float* o = agg + (size_t)node * C + coff;
    *reinterpret_cast<float4*>(o)     = a0;
    *reinterpret_cast<float4*>(o + 4) = a1;
}

// ---------------- fallback: atomic scatter (round-1 proven) ----------------
template<int C>
__global__ __launch_bounds__(256) void scatter_add_k(
    const float* __restrict__ hsrc, const int* __restrict__ src,
    const int* __restrict__ dst, float* __restrict__ agg, int n_edges)
{
    constexpr int Q = C / 4;
    int idx = blockIdx.x * 256 + threadIdx.x;
    int e = idx / Q;
    if (e >= n_edges) return;
    int q = idx - e * Q;
    int s = src[e], d = dst[e];
    const float4 v = *reinterpret_cast<const float4*>(&hsrc[(size_t)s * C + q * 4]);
    float* p = &agg[(size_t)d * C + q * 4];
    unsafeAtomicAdd(p + 0, v.x);
    unsafeAtomicAdd(p + 1, v.y);
    unsafeAtomicAdd(p + 2, v.z);
    unsafeAtomicAdd(p + 3, v.w);
}

// ---------------- fused 2-GEMM MLP (unchanged, proven) ----------------
template<int K1, int N2, bool FINAL_RELU>
__global__ __launch_bounds__(256) void fused_mlp(
    const float* __restrict__ agg, const float* __restrict__ xin,
    const float* __restrict__ Wa, const float* __restrict__ ba,
    const float* __restrict__ Wb, const float* __restrict__ bb,
    float* __restrict__ out, int n_nodes)
{
    __shared__ __align__(16) float sA[32][64];
    __shared__ __align__(16) float sW[32][HIDC];
    __shared__ __align__(16) float sMid[HIDC][64];

    const int tid = threadIdx.x;
    const int tx = tid & 15;
    const int ty = tid >> 4;
    const int r0 = ty * 4;
    const int c0 = tx * 8;
    const int rowBlock = blockIdx.x * 64;

    float acc[4][8];
    #pragma unroll
    for (int i = 0; i < 4; ++i)
        #pragma unroll
        for (int j = 0; j < 8; ++j) acc[i][j] = 0.f;

    for (int kk = 0; kk < K1; kk += 32) {
        #pragma unroll
        for (int i = 0; i < 2; ++i) {
            int f = tid + i * 256;
            int row = f >> 3, c4 = f & 7;
            int grow = rowBlock + row;
            float4 v = make_float4(0.f, 0.f, 0.f, 0.f);
            if (grow < n_nodes) {
                size_t off = (size_t)grow * K1 + kk + c4 * 4;
                float4 a = *reinterpret_cast<const float4*>(agg + off);
                float4 b = *reinterpret_cast<const float4*>(xin + off);
                v.x = a.x + b.x; v.y = a.y + b.y; v.z = a.z + b.z; v.w = a.w + b.w;
            }
            sA[c4 * 4 + 0][row] = v.x;
            sA[c4 * 4 + 1][row] = v.y;
            sA[c4 * 4 + 2][row] = v.z;
            sA[c4 * 4 + 3][row] = v.w;
        }
        #pragma unroll
        for (int i = 0; i < 4; ++i) {
            int f = tid + i * 256;
            int r = f >> 5, c4 = f & 31;
            *reinterpret_cast<float4*>(&sW[r][c4 * 4]) =
                *reinterpret_cast<const float4*>(&Wa[(size_t)(kk + r) * HIDC + c4 * 4]);
        }
        __syncthreads();
        #pragma unroll
        for (int k = 0; k < 32; ++k) {
            float4 a  = *reinterpret_cast<const float4*>(&sA[k][r0]);
            float4 b0 = *reinterpret_cast<const float4*>(&sW[k][c0]);
            float4 b1 = *reinterpret_cast<const float4*>(&sW[k][c0 + 4]);
            float av[4] = {a.x, a.y, a.z, a.w};
            float bv[8] = {b0.x, b0.y, b0.z, b0.w, b1.x, b1.y, b1.z, b1.w};
            #pragma unroll
            for (int i = 0; i < 4; ++i)
                #pragma unroll
                for (int j = 0; j < 8; ++j)
                    acc[i][j] = fmaf(av[i], bv[j], acc[i][j]);
        }
        __syncthreads();
    }
    #pragma unroll
    for (int j = 0; j < 8; ++j) {
        float bj = ba[c0 + j];
        #pragma unroll
        for (int i = 0; i < 4; ++i) {
            float v = fmaxf(acc[i][j] + bj, 0.f);
            sMid[c0 + j][r0 + i] = v;
        }
    }

    constexpr int JW = (N2 == 128) ? 8 : 4;
    const int c02 = tx * JW;
    float acc2[4][JW];
    #pragma unroll
    for (int i = 0; i < 4; ++i)
        #pragma unroll
        for (int j = 0; j < JW; ++j) acc2[i][j] = 0.f;

    for (int kk = 0; kk < HIDC; kk += 32) {
        constexpr int NF4 = 32 * N2 / 4;
        #pragma unroll
        for (int i = 0; i < NF4 / 256; ++i) {
            int f = tid + i * 256;
            int r = f / (N2 / 4), c4 = f % (N2 / 4);
            *reinterpret_cast<float4*>(&sW[r][c4 * 4]) =
                *reinterpret_cast<const float4*>(&Wb[(size_t)(kk + r) * N2 + c4 * 4]);
        }
        __syncthreads();
        #pragma unroll
        for (int k = 0; k < 32; ++k) {
            float4 a = *reinterpret_cast<const float4*>(&sMid[kk + k][r0]);
            float av[4] = {a.x, a.y, a.z, a.w};
            float bv[JW];
            float4 b0 = *reinterpret_cast<const float4*>(&sW[k][c02]);
            bv[0] = b0.x; bv[1] = b0.y; bv[2] = b0.z; bv[3] = b0.w;
            if constexpr (JW == 8) {
                float4 b1 = *reinterpret_cast<const float4*>(&sW[k][c02 + 4]);
                bv[4] = b1.x; bv[5] = b1.y; bv[6] = b1.z; bv[7] = b1.w;
            }
            #pragma unroll
            for (int i = 0; i < 4; ++i)
                #pragma unroll
                for (int j = 0; j < JW; ++j)
                    acc2[i][j] = fmaf(av[i], bv[j], acc2[i][j]);
        }
        __syncthreads();
    }
    #pragma unroll
    for (int i = 0; i < 4; ++i) {
        int grow = rowBlock + r0 + i;
        if (grow < n_nodes) {
            #pragma unroll
            for (int j4 = 0; j4 < JW / 4; ++j4) {
                float4 v;
                v.x = acc2[i][j4 * 4 + 0] + bb[c02 + j4 * 4 + 0];
                v.y = acc2[i][j4 * 4 + 1] + bb[c02 + j4 * 4 + 1];
                v.z = acc2[i][j4 * 4 + 2] + bb[c02 + j4 * 4 + 2];
                v.w = acc2[i][j4 * 4 + 3] + bb[c02 + j4 * 4 + 3];
                if (FINAL_RELU) {
                    v.x = fmaxf(v.x, 0.f); v.y = fmaxf(v.y, 0.f);
                    v.z = fmaxf(v.z, 0.f); v.w = fmaxf(v.w, 0.f);
                }
                *reinterpret_cast<float4*>(&out[(size_t)grow * N2 + c02 + j4 * 4]) = v;
            }
        }
    }
}

extern "C" void kernel_launch(void* const* d_in, const int* in_sizes, int n_in,
                              void* d_out, int out_size, void* d_ws, size_t ws_size,
                              hipStream_t stream)
{
    const float* x   = (const float*)d_in[0];
    const int*   ei  = (const int*)d_in[1];
    const float* W1a = (const float*)d_in[2];
    const float* b1a = (const float*)d_in[3];
    const float* W1b = (const float*)d_in[4];
    const float* b1b = (const float*)d_in[5];
    const float* W2a = (const float*)d_in[6];
    const float* b2a = (const float*)d_in[7];
    const float* W2b = (const float*)d_in[8];
    const float* b2b = (const float*)d_in[9];

    const int n_nodes = in_sizes[0] / 64;
    const int n_edges = in_sizes[1] / 2;
    const int* src = ei;
    const int* dst = ei + n_edges;

    char* ws = (char*)d_ws;
    const size_t featB = (size_t)n_nodes * HIDC * sizeof(float);   // 51.2 MB
    float* agg = (float*)ws;
    float* h   = (float*)(ws + featB);
    float* out = (float*)d_out;

    const int mlp_grid = (n_nodes + 63) / 64;
    const int egrid = (n_edges + 255) / 256;

    // CSR arrays after the two feature buffers
    size_t o = 2 * featB;
    int* eidx = (int*)(ws + o); o += (size_t)n_edges * sizeof(int);
    int* cnt  = (int*)(ws + o); o += (size_t)n_nodes * sizeof(int);
    int* offs = (int*)(ws + o); o += (size_t)n_nodes * sizeof(int);
    int* cur  = (int*)(ws + o); o += (size_t)n_nodes * sizeof(int);
    int* bsum = (int*)(ws + o); o += 256 * sizeof(int);
    const bool use_csr = (ws_size >= o);

    if (use_csr) {
        // ---- build CSR (dst-grouped src list) ----
        hipMemsetAsync(cnt, 0, (size_t)n_nodes * sizeof(int), stream);
        hist_k<<<egrid, 256, 0, stream>>>(dst, cnt, n_edges);
        const int nb = (n_nodes + 2047) / 2048;   // <= 256 required
        scan_block_k<<<nb, 256, 0, stream>>>(cnt, offs, bsum, n_nodes);
        scan_bsum_k<<<1, 256, 0, stream>>>(bsum, nb);
        scan_add_k<<<nb, 256, 0, stream>>>(offs, cur, bsum, n_nodes);
        fill_k<<<egrid, 256, 0, stream>>>(src, dst, cur, eidx, n_edges);

        // ---- layer 1 ----
        gather_agg_k<64><<<(n_nodes + 31) / 32, 256, 0, stream>>>(
            x, offs, cnt, eidx, agg, n_nodes);
        fused_mlp<64, 128, true><<<mlp_grid, 256, 0, stream>>>(
            agg, x, W1a, b1a, W1b, b1b, h, n_nodes);

        // ---- layer 2 ----
        gather_agg_k<128><<<(n_nodes + 15) / 16, 256, 0, stream>>>(
            h, offs, cnt, eidx, agg, n_nodes);
        fused_mlp<128, 64, false><<<mlp_grid, 256, 0, stream>>>(
            agg, h, W2a, b2a, W2b, b2b, out, n_nodes);
    } else {
        // ---- fallback: round-1 atomic scatter path ----
        hipMemsetAsync(agg, 0, (size_t)n_nodes * 64 * sizeof(float), stream);
        scatter_add_k<64><<<(n_edges * 16 + 255) / 256, 256, 0, stream>>>(
            x, src, dst, agg, n_edges);
        fused_mlp<64, 128, true><<<mlp_grid, 256, 0, stream>>>(
            agg, x, W1a, b1a, W1b, b1b, h, n_nodes);

        hipMemsetAsync(agg, 0, (size_t)n_nodes * HIDC * sizeof(float), stream);
        scatter_add_k<128><<<(n_edges * 32 + 255) / 256, 256, 0, stream>>>(
            h, src, dst, agg, n_edges);
        fused_mlp<128, 64, false><<<mlp_grid, 256, 0, stream>>>(
            agg, h, W2a, b2a, W2b, b2b, out, n_nodes);
    }
}

// Round 3
// 365.750 us; speedup vs baseline: 11.8161x; 1.7617x over previous
//
#include <hip/hip_runtime.h>
#include <hip/hip_bf16.h>

// GIN 2-layer, bf16 feature pipeline + MFMA MLPs.
// Per layer: A = sum_{nbr} h[nbr] + h[self] (CSR gather, f32 acc, bf16 out);
//            out = [relu]( relu(A@Wa+ba) @ Wb + bb ).

typedef short  bf16x8 __attribute__((ext_vector_type(8)));
typedef float  f32x4  __attribute__((ext_vector_type(4)));

__device__ inline float bf2f(unsigned short u) {
    unsigned int t = ((unsigned int)u) << 16;
    return __builtin_bit_cast(float, t);
}
__device__ inline unsigned short f2bf(float f) {   // round-to-nearest-even
    unsigned int u = __builtin_bit_cast(unsigned int, f);
    u += 0x7fffu + ((u >> 16) & 1u);
    return (unsigned short)(u >> 16);
}

// ---------------- prep: f32 -> bf16 feature convert ----------------
__global__ __launch_bounds__(256) void cvt_bf16_k(
    const float* __restrict__ x, unsigned short* __restrict__ xb, int n8)
{
    int i = blockIdx.x * 256 + threadIdx.x;
    if (i >= n8) return;
    const float4* p = reinterpret_cast<const float4*>(x + (size_t)i * 8);
    float4 a = p[0], b = p[1];
    union { unsigned short us[8]; uint4 v; } o;
    o.us[0] = f2bf(a.x); o.us[1] = f2bf(a.y); o.us[2] = f2bf(a.z); o.us[3] = f2bf(a.w);
    o.us[4] = f2bf(b.x); o.us[5] = f2bf(b.y); o.us[6] = f2bf(b.z); o.us[7] = f2bf(b.w);
    *reinterpret_cast<uint4*>(xb + (size_t)i * 8) = o.v;
}

// ---------------- prep: weight transpose+convert: WT[n][k] = bf16(W[k][n]) ----
__global__ __launch_bounds__(256) void wt_prep_k(
    const float* __restrict__ W, unsigned short* __restrict__ WT, int K, int N)
{
    int idx = blockIdx.x * 256 + threadIdx.x;
    if (idx >= N * K) return;
    int n = idx / K, k = idx - n * K;
    WT[idx] = f2bf(W[(size_t)k * N + n]);
}

// ---------------- CSR build (proven in round 2) ----------------
__global__ __launch_bounds__(256) void hist_k(
    const int* __restrict__ dst, int* __restrict__ cnt, int n_edges)
{
    int e = blockIdx.x * 256 + threadIdx.x;
    if (e < n_edges) atomicAdd(&cnt[dst[e]], 1);
}

__global__ __launch_bounds__(256) void scan_block_k(
    const int* __restrict__ cnt, int* __restrict__ offs, int* __restrict__ bsum, int n)
{
    __shared__ int s[256];
    const int tid = threadIdx.x;
    const int base = blockIdx.x * 2048 + tid * 8;
    int v[8]; int tsum = 0;
    #pragma unroll
    for (int j = 0; j < 8; ++j) {
        int idx = base + j;
        v[j] = (idx < n) ? cnt[idx] : 0;
        tsum += v[j];
    }
    s[tid] = tsum; __syncthreads();
    #pragma unroll
    for (int d = 1; d < 256; d <<= 1) {
        int t = (tid >= d) ? s[tid - d] : 0;
        __syncthreads();
        s[tid] += t;
        __syncthreads();
    }
    int run = s[tid] - tsum;
    #pragma unroll
    for (int j = 0; j < 8; ++j) {
        int idx = base + j;
        if (idx < n) offs[idx] = run;
        run += v[j];
    }
    if (tid == 255) bsum[blockIdx.x] = s[255];
}

__global__ __launch_bounds__(256) void scan_bsum_k(int* __restrict__ bsum, int nb)
{
    __shared__ int s[256];
    const int tid = threadIdx.x;
    int v = (tid < nb) ? bsum[tid] : 0;
    s[tid] = v; __syncthreads();
    #pragma unroll
    for (int d = 1; d < 256; d <<= 1) {
        int t = (tid >= d) ? s[tid - d] : 0;
        __syncthreads();
        s[tid] += t;
        __syncthreads();
    }
    if (tid < nb) bsum[tid] = s[tid] - v;
}

__global__ __launch_bounds__(256) void scan_add_k(
    int* __restrict__ offs, int* __restrict__ cur, const int* __restrict__ bsum, int n)
{
    const int b = bsum[blockIdx.x];
    const int base = blockIdx.x * 2048 + threadIdx.x * 8;
    #pragma unroll
    for (int j = 0; j < 8; ++j) {
        int idx = base + j;
        if (idx < n) { int o = offs[idx] + b; offs[idx] = o; cur[idx] = o; }
    }
}

__global__ __launch_bounds__(256) void fill_k(
    const int* __restrict__ src, const int* __restrict__ dst,
    int* __restrict__ cur, int* __restrict__ eidx, int n_edges)
{
    int e = blockIdx.x * 256 + threadIdx.x;
    if (e < n_edges) {
        int p = atomicAdd(&cur[dst[e]], 1);
        eidx[p] = src[e];
    }
}

// ---------------- gather aggregation: A = sum(nbrs) + self, bf16 out ----------
template<int C>
__global__ __launch_bounds__(256) void gather_agg_k(
    const unsigned short* __restrict__ h, const int* __restrict__ offs,
    const int* __restrict__ cnt, const int* __restrict__ eidx,
    unsigned short* __restrict__ A, int n_nodes)
{
    constexpr int TPN = C / 8;
    constexpr int NPB = 256 / TPN;
    const int node = blockIdx.x * NPB + threadIdx.x / TPN;
    const int lane = threadIdx.x % TPN;
    if (node >= n_nodes) return;
    const size_t coff = (size_t)lane * 8;

    float acc[8];
    {   // self contribution (GIN eps=0: (1+eps)*x = x)
        uint4 v = *reinterpret_cast<const uint4*>(h + (size_t)node * C + coff);
        const unsigned short* u = (const unsigned short*)&v;
        #pragma unroll
        for (int j = 0; j < 8; ++j) acc[j] = bf2f(u[j]);
    }
    const int beg = offs[node], end = beg + cnt[node];
    int p = beg;
    for (; p + 2 <= end; p += 2) {
        int s0 = eidx[p], s1 = eidx[p + 1];
        uint4 v0 = *reinterpret_cast<const uint4*>(h + (size_t)s0 * C + coff);
        uint4 v1 = *reinterpret_cast<const uint4*>(h + (size_t)s1 * C + coff);
        const unsigned short* u0 = (const unsigned short*)&v0;
        const unsigned short* u1 = (const unsigned short*)&v1;
        #pragma unroll
        for (int j = 0; j < 8; ++j) acc[j] += bf2f(u0[j]) + bf2f(u1[j]);
    }
    if (p < end) {
        uint4 v0 = *reinterpret_cast<const uint4*>(h + (size_t)eidx[p] * C + coff);
        const unsigned short* u0 = (const unsigned short*)&v0;
        #pragma unroll
        for (int j = 0; j < 8; ++j) acc[j] += bf2f(u0[j]);
    }
    union { unsigned short us[8]; uint4 v; } o;
    #pragma unroll
    for (int j = 0; j < 8; ++j) o.us[j] = f2bf(acc[j]);
    *reinterpret_cast<uint4*>(A + (size_t)node * C + coff) = o.v;
}

// ---------------- fused 2-GEMM MLP via MFMA bf16 ----------------
// Block = 256 thr (4 waves), 64-row tile; wave w owns rows w*16..w*16+15.
// Entire K resident in LDS; weights staged whole (transposed bf16 from global).
// XOR swizzle byte ^= ((row&7)<<4) keeps all frag ds_read_b128 conflict-minimal.
template<int K1, int N2, bool RELU_OUT, bool OUT_BF16>
__global__ __launch_bounds__(256) void mlp_mfma_k(
    const unsigned short* __restrict__ Ain,   // [n][K1] bf16
    const unsigned short* __restrict__ WTa,   // [128][K1] bf16 transposed
    const float* __restrict__ ba,             // [128]
    const unsigned short* __restrict__ WTb,   // [N2][128] bf16 transposed
    const float* __restrict__ bb,             // [N2]
    void* __restrict__ outp, int n_nodes)
{
    constexpr int KS1 = K1 / 32;
    constexpr int NT2 = N2 / 16;
    static_assert(64 * N2 * (OUT_BF16 ? 2 : 4) <= 64 * 128 * 2, "out staging fits sMid");

    __shared__ unsigned short sA[64 * K1];
    __shared__ unsigned short sWa[128 * K1];
    __shared__ unsigned short sWb[N2 * 128];
    __shared__ unsigned short sMid[64 * 128];

    const int tid = threadIdx.x;
    const int wave = tid >> 6, lane = tid & 63;
    const int rc = lane & 15;       // row (A/C) or col (B) within 16-tile
    const int kg = lane >> 4;       // k-group 0..3 (8 bf16 each)
    const int rowBlock = blockIdx.x * 64;

    // ---- stage A tile (guarded rows), swizzled ----
    {
        constexpr int CPR = K1 / 8;                   // 16B chunks per row
        #pragma unroll
        for (int f = tid; f < 64 * CPR; f += 256) {
            int r = f / CPR, c = f - r * CPR;
            uint4 v = make_uint4(0u, 0u, 0u, 0u);
            int gr = rowBlock + r;
            if (gr < n_nodes)
                v = *reinterpret_cast<const uint4*>(Ain + (size_t)gr * K1 + c * 8);
            int byte = r * (K1 * 2) + ((c * 16) ^ ((r & 7) << 4));
            *reinterpret_cast<uint4*>((char*)sA + byte) = v;
        }
    }
    // ---- stage WTa [128][K1], swizzled ----
    {
        constexpr int CPR = K1 / 8;
        #pragma unroll
        for (int f = tid; f < 128 * CPR; f += 256) {
            int r = f / CPR, c = f - r * CPR;
            uint4 v = *reinterpret_cast<const uint4*>(WTa + (size_t)r * K1 + c * 8);
            int byte = r * (K1 * 2) + ((c * 16) ^ ((r & 7) << 4));
            *reinterpret_cast<uint4*>((char*)sWa + byte) = v;
        }
    }
    // ---- stage WTb [N2][128], swizzled ----
    {
        #pragma unroll
        for (int f = tid; f < N2 * 16; f += 256) {
            int r = f / 16, c = f - r * 16;
            uint4 v = *reinterpret_cast<const uint4*>(WTb + (size_t)r * 128 + c * 8);
            int byte = r * 256 + ((c * 16) ^ ((r & 7) << 4));
            *reinterpret_cast<uint4*>((char*)sWb + byte) = v;
        }
    }
    __syncthreads();

    // ---- GEMM1: (64 x K1) @ (K1 x 128) ----
    f32x4 acc1[8];
    #pragma unroll
    for (int n = 0; n < 8; ++n) acc1[n] = (f32x4){0.f, 0.f, 0.f, 0.f};
    bf16x8 af[KS1];
    #pragma unroll
    for (int ks = 0; ks < KS1; ++ks) {
        int r = wave * 16 + rc;
        int byte = r * (K1 * 2) + (((ks * 32 + kg * 8) * 2) ^ ((r & 7) << 4));
        af[ks] = *reinterpret_cast<const bf16x8*>((const char*)sA + byte);
    }
    #pragma unroll
    for (int n = 0; n < 8; ++n) {
        int c = n * 16 + rc;
        #pragma unroll
        for (int ks = 0; ks < KS1; ++ks) {
            int byte = c * (K1 * 2) + (((ks * 32 + kg * 8) * 2) ^ ((c & 7) << 4));
            bf16x8 bfr = *reinterpret_cast<const bf16x8*>((const char*)sWa + byte);
            acc1[n] = __builtin_amdgcn_mfma_f32_16x16x32_bf16(af[ks], bfr, acc1[n], 0, 0, 0);
        }
    }
    // epilogue 1: bias + relu -> sMid bf16 [64][128] swizzled
    // C-frag: row = kg*4 + i, col = rc (per n-tile)
    #pragma unroll
    for (int n = 0; n < 8; ++n) {
        int c = n * 16 + rc;
        float bias = ba[c];
        #pragma unroll
        for (int i = 0; i < 4; ++i) {
            int r = wave * 16 + kg * 4 + i;
            float v = fmaxf(acc1[n][i] + bias, 0.f);
            int byte = r * 256 + ((c * 2) ^ ((r & 7) << 4));
            *reinterpret_cast<unsigned short*>((char*)sMid + byte) = f2bf(v);
        }
    }
    __syncthreads();

    // ---- GEMM2: (64 x 128) @ (128 x N2) ----
    f32x4 acc2[NT2];
    #pragma unroll
    for (int n = 0; n < NT2; ++n) acc2[n] = (f32x4){0.f, 0.f, 0.f, 0.f};
    bf16x8 mf[4];
    #pragma unroll
    for (int ks = 0; ks < 4; ++ks) {
        int r = wave * 16 + rc;
        int byte = r * 256 + (((ks * 32 + kg * 8) * 2) ^ ((r & 7) << 4));
        mf[ks] = *reinterpret_cast<const bf16x8*>((const char*)sMid + byte);
    }
    #pragma unroll
    for (int n = 0; n < NT2; ++n) {
        int c = n * 16 + rc;
        #pragma unroll
        for (int ks = 0; ks < 4; ++ks) {
            int byte = c * 256 + (((ks * 32 + kg * 8) * 2) ^ ((c & 7) << 4));
            bf16x8 bfr = *reinterpret_cast<const bf16x8*>((const char*)sWb + byte);
            acc2[n] = __builtin_amdgcn_mfma_f32_16x16x32_bf16(mf[ks], bfr, acc2[n], 0, 0, 0);
        }
    }
    __syncthreads();   // all sMid reads done before reuse as out staging

    // ---- epilogue 2: bias [+relu] -> staging -> coalesced global store ----
    if constexpr (OUT_BF16) {
        #pragma unroll
        for (int n = 0; n < NT2; ++n) {
            int c = n * 16 + rc;
            float bias = bb[c];
            #pragma unroll
            for (int i = 0; i < 4; ++i) {
                int r = wave * 16 + kg * 4 + i;
                float v = acc2[n][i] + bias;
                if (RELU_OUT) v = fmaxf(v, 0.f);
                sMid[r * N2 + c] = f2bf(v);
            }
        }
        __syncthreads();
        unsigned short* out = (unsigned short*)outp;
        constexpr int CPR = N2 / 8;
        #pragma unroll
        for (int f = tid; f < 64 * CPR; f += 256) {
            int r = f / CPR, c = f - r * CPR;
            int gr = rowBlock + r;
            if (gr < n_nodes)
                *reinterpret_cast<uint4*>(out + (size_t)gr * N2 + c * 8) =
                    *reinterpret_cast<const uint4*>(sMid + r * N2 + c * 8);
        }
    } else {
        float* sOut = reinterpret_cast<float*>(sMid);   // [64][N2] f32
        #pragma unroll
        for (int n = 0; n < NT2; ++n) {
            int c = n * 16 + rc;
            float bias = bb[c];
            #pragma unroll
            for (int i = 0; i < 4; ++i) {
                int r = wave * 16 + kg * 4 + i;
                float v = acc2[n][i] + bias;
                if (RELU_OUT) v = fmaxf(v, 0.f);
                sOut[r * N2 + c] = v;
            }
        }
        __syncthreads();
        float* out = (float*)outp;
        constexpr int CPR = N2 / 4;
        #pragma unroll
        for (int f = tid; f < 64 * CPR; f += 256) {
            int r = f / CPR, c = f - r * CPR;
            int gr = rowBlock + r;
            if (gr < n_nodes)
                *reinterpret_cast<float4*>(out + (size_t)gr * N2 + c * 4) =
                    *reinterpret_cast<const float4*>(sOut + r * N2 + c * 4);
        }
    }
}

extern "C" void kernel_launch(void* const* d_in, const int* in_sizes, int n_in,
                              void* d_out, int out_size, void* d_ws, size_t ws_size,
                              hipStream_t stream)
{
    const float* x   = (const float*)d_in[0];
    const int*   ei  = (const int*)d_in[1];
    const float* W1a = (const float*)d_in[2];
    const float* b1a = (const float*)d_in[3];
    const float* W1b = (const float*)d_in[4];
    const float* b1b = (const float*)d_in[5];
    const float* W2a = (const float*)d_in[6];
    const float* b2a = (const float*)d_in[7];
    const float* W2b = (const float*)d_in[8];
    const float* b2b = (const float*)d_in[9];

    const int n_nodes = in_sizes[0] / 64;
    const int n_edges = in_sizes[1] / 2;
    const int* src = ei;
    const int* dst = ei + n_edges;

    char* ws = (char*)d_ws;
    size_t o = 0;
    auto alloc = [&](size_t bytes) -> char* {
        char* p = ws + o;
        o += (bytes + 255) & ~(size_t)255;
        return p;
    };
    unsigned short* A    = (unsigned short*)alloc((size_t)n_nodes * 128 * 2);
    unsigned short* h    = (unsigned short*)alloc((size_t)n_nodes * 128 * 2);
    unsigned short* xb   = (unsigned short*)alloc((size_t)n_nodes * 64 * 2);
    int* eidx = (int*)alloc((size_t)n_edges * 4);
    int* cnt  = (int*)alloc((size_t)n_nodes * 4);
    int* offs = (int*)alloc((size_t)n_nodes * 4);
    int* cur  = (int*)alloc((size_t)n_nodes * 4);
    int* bsum = (int*)alloc(256 * 4);
    unsigned short* WT1a = (unsigned short*)alloc(64 * 128 * 2);
    unsigned short* WT1b = (unsigned short*)alloc(128 * 128 * 2);
    unsigned short* WT2a = (unsigned short*)alloc(128 * 128 * 2);
    unsigned short* WT2b = (unsigned short*)alloc(128 * 64 * 2);

    const int egrid = (n_edges + 255) / 256;
    const int mlp_grid = (n_nodes + 63) / 64;

    // ---- prep: bf16 conversions ----
    cvt_bf16_k<<<(n_nodes * 8 + 255) / 256, 256, 0, stream>>>(x, xb, n_nodes * 8);
    wt_prep_k<<<(64 * 128 + 255) / 256, 256, 0, stream>>>(W1a, WT1a, 64, 128);
    wt_prep_k<<<(128 * 128 + 255) / 256, 256, 0, stream>>>(W1b, WT1b, 128, 128);
    wt_prep_k<<<(128 * 128 + 255) / 256, 256, 0, stream>>>(W2a, WT2a, 128, 128);
    wt_prep_k<<<(128 * 64 + 255) / 256, 256, 0, stream>>>(W2b, WT2b, 128, 64);

    // ---- CSR build ----
    hipMemsetAsync(cnt, 0, (size_t)n_nodes * sizeof(int), stream);
    hist_k<<<egrid, 256, 0, stream>>>(dst, cnt, n_edges);
    const int nb = (n_nodes + 2047) / 2048;
    scan_block_k<<<nb, 256, 0, stream>>>(cnt, offs, bsum, n_nodes);
    scan_bsum_k<<<1, 256, 0, stream>>>(bsum, nb);
    scan_add_k<<<nb, 256, 0, stream>>>(offs, cur, bsum, n_nodes);
    fill_k<<<egrid, 256, 0, stream>>>(src, dst, cur, eidx, n_edges);

    // ---- layer 1 ----
    gather_agg_k<64><<<(n_nodes + 31) / 32, 256, 0, stream>>>(
        xb, offs, cnt, eidx, A, n_nodes);
    mlp_mfma_k<64, 128, true, true><<<mlp_grid, 256, 0, stream>>>(
        A, WT1a, b1a, WT1b, b1b, h, n_nodes);

    // ---- layer 2 ----
    gather_agg_k<128><<<(n_nodes + 15) / 16, 256, 0, stream>>>(
        h, offs, cnt, eidx, A, n_nodes);
    mlp_mfma_k<128, 64, false, false><<<mlp_grid, 256, 0, stream>>>(
        A, WT2a, b2a, WT2b, b2b, d_out, n_nodes);
}

// Round 4
// 311.676 us; speedup vs baseline: 13.8661x; 1.1735x over previous
//
#include <hip/hip_runtime.h>
#include <hip/hip_bf16.h>

// GIN 2-layer, bf16 feature pipeline + MFMA MLPs.
// CSR build with XCD-segmented fill (kills the 16x eidx write amplification).

#define NSEG 8

typedef short  bf16x8 __attribute__((ext_vector_type(8)));
typedef float  f32x4  __attribute__((ext_vector_type(4)));

__device__ inline float bf2f(unsigned short u) {
    unsigned int t = ((unsigned int)u) << 16;
    return __builtin_bit_cast(float, t);
}
__device__ inline unsigned short f2bf(float f) {   // round-to-nearest-even
    unsigned int u = __builtin_bit_cast(unsigned int, f);
    u += 0x7fffu + ((u >> 16) & 1u);
    return (unsigned short)(u >> 16);
}

// ---------------- prep: f32 -> bf16 feature convert ----------------
__global__ __launch_bounds__(256) void cvt_bf16_k(
    const float* __restrict__ x, unsigned short* __restrict__ xb, int n8)
{
    int i = blockIdx.x * 256 + threadIdx.x;
    if (i >= n8) return;
    const float4* p = reinterpret_cast<const float4*>(x + (size_t)i * 8);
    float4 a = p[0], b = p[1];
    union { unsigned short us[8]; uint4 v; } o;
    o.us[0] = f2bf(a.x); o.us[1] = f2bf(a.y); o.us[2] = f2bf(a.z); o.us[3] = f2bf(a.w);
    o.us[4] = f2bf(b.x); o.us[5] = f2bf(b.y); o.us[6] = f2bf(b.z); o.us[7] = f2bf(b.w);
    *reinterpret_cast<uint4*>(xb + (size_t)i * 8) = o.v;
}

// ---------------- prep: all 4 weight transposes in one launch ----------------
// WT[n][k] = bf16(W[k][n]).  Regions: W1a 64x128, W1b 128x128, W2a 128x128, W2b 128x64.
__global__ __launch_bounds__(256) void wt_prep_all_k(
    const float* __restrict__ W1a, const float* __restrict__ W1b,
    const float* __restrict__ W2a, const float* __restrict__ W2b,
    unsigned short* __restrict__ T1a, unsigned short* __restrict__ T1b,
    unsigned short* __restrict__ T2a, unsigned short* __restrict__ T2b)
{
    int idx = blockIdx.x * 256 + threadIdx.x;
    const float* W; unsigned short* T; int K, N;
    if (idx < 8192)        { W = W1a; T = T1a; K = 64;  N = 128; }
    else if (idx < 24576)  { idx -= 8192;  W = W1b; T = T1b; K = 128; N = 128; }
    else if (idx < 40960)  { idx -= 24576; W = W2a; T = T2a; K = 128; N = 128; }
    else if (idx < 49152)  { idx -= 40960; W = W2b; T = T2b; K = 128; N = 64; }
    else return;
    int n = idx / K, k = idx - n * K;
    T[idx] = f2bf(W[(size_t)k * N + n]);
}

// ---------------- CSR build, XCD-segmented ----------------
// seg = blockIdx & 7 -> lands on one XCD (round-robin dispatch); all updates to
// a node-range segment come from one XCD so its cnt/eidx lines stay L2-resident.
__global__ __launch_bounds__(256) void hist_seg_k(
    const int* __restrict__ dst, int* __restrict__ cnt, int n_edges, int segN)
{
    const int seg = blockIdx.x & (NSEG - 1);
    const int chunk = blockIdx.x >> 3;
    const int nchunks = gridDim.x >> 3;
    const int lo = seg * segN, hi = lo + segN;
    for (int e = chunk * 256 + threadIdx.x; e < n_edges; e += nchunks * 256) {
        int d = dst[e];
        if (d >= lo && d < hi) atomicAdd(&cnt[d], 1);
    }
}

__global__ __launch_bounds__(256) void fill_seg_k(
    const int* __restrict__ src, const int* __restrict__ dst,
    int* __restrict__ cur, int* __restrict__ eidx, int n_edges, int segN)
{
    const int seg = blockIdx.x & (NSEG - 1);
    const int chunk = blockIdx.x >> 3;
    const int nchunks = gridDim.x >> 3;
    const int lo = seg * segN, hi = lo + segN;
    for (int e = chunk * 256 + threadIdx.x; e < n_edges; e += nchunks * 256) {
        int d = dst[e];
        if (d >= lo && d < hi) {
            int p = atomicAdd(&cur[d], 1);
            eidx[p] = src[e];
        }
    }
}

// ---------------- scans (proven) ----------------
__global__ __launch_bounds__(256) void scan_block_k(
    const int* __restrict__ cnt, int* __restrict__ offs, int* __restrict__ bsum, int n)
{
    __shared__ int s[256];
    const int tid = threadIdx.x;
    const int base = blockIdx.x * 2048 + tid * 8;
    int v[8]; int tsum = 0;
    #pragma unroll
    for (int j = 0; j < 8; ++j) {
        int idx = base + j;
        v[j] = (idx < n) ? cnt[idx] : 0;
        tsum += v[j];
    }
    s[tid] = tsum; __syncthreads();
    #pragma unroll
    for (int d = 1; d < 256; d <<= 1) {
        int t = (tid >= d) ? s[tid - d] : 0;
        __syncthreads();
        s[tid] += t;
        __syncthreads();
    }
    int run = s[tid] - tsum;
    #pragma unroll
    for (int j = 0; j < 8; ++j) {
        int idx = base + j;
        if (idx < n) offs[idx] = run;
        run += v[j];
    }
    if (tid == 255) bsum[blockIdx.x] = s[255];
}

__global__ __launch_bounds__(256) void scan_bsum_k(int* __restrict__ bsum, int nb)
{
    __shared__ int s[256];
    const int tid = threadIdx.x;
    int v = (tid < nb) ? bsum[tid] : 0;
    s[tid] = v; __syncthreads();
    #pragma unroll
    for (int d = 1; d < 256; d <<= 1) {
        int t = (tid >= d) ? s[tid - d] : 0;
        __syncthreads();
        s[tid] += t;
        __syncthreads();
    }
    if (tid < nb) bsum[tid] = s[tid] - v;
}

__global__ __launch_bounds__(256) void scan_add_k(
    int* __restrict__ offs, int* __restrict__ cur, const int* __restrict__ bsum, int n)
{
    const int b = bsum[blockIdx.x];
    const int base = blockIdx.x * 2048 + threadIdx.x * 8;
    #pragma unroll
    for (int j = 0; j < 8; ++j) {
        int idx = base + j;
        if (idx < n) { int o = offs[idx] + b; offs[idx] = o; cur[idx] = o; }
    }
}

// ---------------- gather aggregation: A = sum(nbrs) + self, bf16 out ----------
template<int C>
__global__ __launch_bounds__(256) void gather_agg_k(
    const unsigned short* __restrict__ h, const int* __restrict__ offs,
    const int* __restrict__ cnt, const int* __restrict__ eidx,
    unsigned short* __restrict__ A, int n_nodes)
{
    constexpr int TPN = C / 8;
    constexpr int NPB = 256 / TPN;
    const int node = blockIdx.x * NPB + threadIdx.x / TPN;
    const int lane = threadIdx.x % TPN;
    if (node >= n_nodes) return;
    const size_t coff = (size_t)lane * 8;

    float acc[8];
    {   // self contribution (GIN eps=0)
        uint4 v = *reinterpret_cast<const uint4*>(h + (size_t)node * C + coff);
        const unsigned short* u = (const unsigned short*)&v;
        #pragma unroll
        for (int j = 0; j < 8; ++j) acc[j] = bf2f(u[j]);
    }
    const int beg = offs[node], end = beg + cnt[node];
    int p = beg;
    for (; p + 2 <= end; p += 2) {
        int s0 = eidx[p], s1 = eidx[p + 1];
        uint4 v0 = *reinterpret_cast<const uint4*>(h + (size_t)s0 * C + coff);
        uint4 v1 = *reinterpret_cast<const uint4*>(h + (size_t)s1 * C + coff);
        const unsigned short* u0 = (const unsigned short*)&v0;
        const unsigned short* u1 = (const unsigned short*)&v1;
        #pragma unroll
        for (int j = 0; j < 8; ++j) acc[j] += bf2f(u0[j]) + bf2f(u1[j]);
    }
    if (p < end) {
        uint4 v0 = *reinterpret_cast<const uint4*>(h + (size_t)eidx[p] * C + coff);
        const unsigned short* u0 = (const unsigned short*)&v0;
        #pragma unroll
        for (int j = 0; j < 8; ++j) acc[j] += bf2f(u0[j]);
    }
    union { unsigned short us[8]; uint4 v; } o;
    #pragma unroll
    for (int j = 0; j < 8; ++j) o.us[j] = f2bf(acc[j]);
    *reinterpret_cast<uint4*>(A + (size_t)node * C + coff) = o.v;
}

// ---------------- fused 2-GEMM MLP via MFMA bf16 (proven round 3) ----------------
template<int K1, int N2, bool RELU_OUT, bool OUT_BF16>
__global__ __launch_bounds__(256) void mlp_mfma_k(
    const unsigned short* __restrict__ Ain,
    const unsigned short* __restrict__ WTa,
    const float* __restrict__ ba,
    const unsigned short* __restrict__ WTb,
    const float* __restrict__ bb,
    void* __restrict__ outp, int n_nodes)
{
    constexpr int KS1 = K1 / 32;
    constexpr int NT2 = N2 / 16;
    static_assert(64 * N2 * (OUT_BF16 ? 2 : 4) <= 64 * 128 * 2, "out staging fits sMid");

    __shared__ unsigned short sA[64 * K1];
    __shared__ unsigned short sWa[128 * K1];
    __shared__ unsigned short sWb[N2 * 128];
    __shared__ unsigned short sMid[64 * 128];

    const int tid = threadIdx.x;
    const int wave = tid >> 6, lane = tid & 63;
    const int rc = lane & 15;
    const int kg = lane >> 4;
    const int rowBlock = blockIdx.x * 64;

    {   // stage A (guarded rows), swizzled
        constexpr int CPR = K1 / 8;
        #pragma unroll
        for (int f = tid; f < 64 * CPR; f += 256) {
            int r = f / CPR, c = f - r * CPR;
            uint4 v = make_uint4(0u, 0u, 0u, 0u);
            int gr = rowBlock + r;
            if (gr < n_nodes)
                v = *reinterpret_cast<const uint4*>(Ain + (size_t)gr * K1 + c * 8);
            int byte = r * (K1 * 2) + ((c * 16) ^ ((r & 7) << 4));
            *reinterpret_cast<uint4*>((char*)sA + byte) = v;
        }
    }
    {   // stage WTa [128][K1], swizzled
        constexpr int CPR = K1 / 8;
        #pragma unroll
        for (int f = tid; f < 128 * CPR; f += 256) {
            int r = f / CPR, c = f - r * CPR;
            uint4 v = *reinterpret_cast<const uint4*>(WTa + (size_t)r * K1 + c * 8);
            int byte = r * (K1 * 2) + ((c * 16) ^ ((r & 7) << 4));
            *reinterpret_cast<uint4*>((char*)sWa + byte) = v;
        }
    }
    {   // stage WTb [N2][128], swizzled
        #pragma unroll
        for (int f = tid; f < N2 * 16; f += 256) {
            int r = f / 16, c = f - r * 16;
            uint4 v = *reinterpret_cast<const uint4*>(WTb + (size_t)r * 128 + c * 8);
            int byte = r * 256 + ((c * 16) ^ ((r & 7) << 4));
            *reinterpret_cast<uint4*>((char*)sWb + byte) = v;
        }
    }
    __syncthreads();

    // GEMM1: (64 x K1) @ (K1 x 128)
    f32x4 acc1[8];
    #pragma unroll
    for (int n = 0; n < 8; ++n) acc1[n] = (f32x4){0.f, 0.f, 0.f, 0.f};
    bf16x8 af[KS1];
    #pragma unroll
    for (int ks = 0; ks < KS1; ++ks) {
        int r = wave * 16 + rc;
        int byte = r * (K1 * 2) + (((ks * 32 + kg * 8) * 2) ^ ((r & 7) << 4));
        af[ks] = *reinterpret_cast<const bf16x8*>((const char*)sA + byte);
    }
    #pragma unroll
    for (int n = 0; n < 8; ++n) {
        int c = n * 16 + rc;
        #pragma unroll
        for (int ks = 0; ks < KS1; ++ks) {
            int byte = c * (K1 * 2) + (((ks * 32 + kg * 8) * 2) ^ ((c & 7) << 4));
            bf16x8 bfr = *reinterpret_cast<const bf16x8*>((const char*)sWa + byte);
            acc1[n] = __builtin_amdgcn_mfma_f32_16x16x32_bf16(af[ks], bfr, acc1[n], 0, 0, 0);
        }
    }
    // epilogue 1: bias + relu -> sMid bf16 swizzled
    #pragma unroll
    for (int n = 0; n < 8; ++n) {
        int c = n * 16 + rc;
        float bias = ba[c];
        #pragma unroll
        for (int i = 0; i < 4; ++i) {
            int r = wave * 16 + kg * 4 + i;
            float v = fmaxf(acc1[n][i] + bias, 0.f);
            int byte = r * 256 + ((c * 2) ^ ((r & 7) << 4));
            *reinterpret_cast<unsigned short*>((char*)sMid + byte) = f2bf(v);
        }
    }
    __syncthreads();

    // GEMM2: (64 x 128) @ (128 x N2)
    f32x4 acc2[NT2];
    #pragma unroll
    for (int n = 0; n < NT2; ++n) acc2[n] = (f32x4){0.f, 0.f, 0.f, 0.f};
    bf16x8 mf[4];
    #pragma unroll
    for (int ks = 0; ks < 4; ++ks) {
        int r = wave * 16 + rc;
        int byte = r * 256 + (((ks * 32 + kg * 8) * 2) ^ ((r & 7) << 4));
        mf[ks] = *reinterpret_cast<const bf16x8*>((const char*)sMid + byte);
    }
    #pragma unroll
    for (int n = 0; n < NT2; ++n) {
        int c = n * 16 + rc;
        #pragma unroll
        for (int ks = 0; ks < 4; ++ks) {
            int byte = c * 256 + (((ks * 32 + kg * 8) * 2) ^ ((c & 7) << 4));
            bf16x8 bfr = *reinterpret_cast<const bf16x8*>((const char*)sWb + byte);
            acc2[n] = __builtin_amdgcn_mfma_f32_16x16x32_bf16(mf[ks], bfr, acc2[n], 0, 0, 0);
        }
    }
    __syncthreads();

    // epilogue 2: bias [+relu] -> staging -> coalesced store
    if constexpr (OUT_BF16) {
        #pragma unroll
        for (int n = 0; n < NT2; ++n) {
            int c = n * 16 + rc;
            float bias = bb[c];
            #pragma unroll
            for (int i = 0; i < 4; ++i) {
                int r = wave * 16 + kg * 4 + i;
                float v = acc2[n][i] + bias;
                if (RELU_OUT) v = fmaxf(v, 0.f);
                sMid[r * N2 + c] = f2bf(v);
            }
        }
        __syncthreads();
        unsigned short* out = (unsigned short*)outp;
        constexpr int CPR = N2 / 8;
        #pragma unroll
        for (int f = tid; f < 64 * CPR; f += 256) {
            int r = f / CPR, c = f - r * CPR;
            int gr = rowBlock + r;
            if (gr < n_nodes)
                *reinterpret_cast<uint4*>(out + (size_t)gr * N2 + c * 8) =
                    *reinterpret_cast<const uint4*>(sMid + r * N2 + c * 8);
        }
    } else {
        float* sOut = reinterpret_cast<float*>(sMid);
        #pragma unroll
        for (int n = 0; n < NT2; ++n) {
            int c = n * 16 + rc;
            float bias = bb[c];
            #pragma unroll
            for (int i = 0; i < 4; ++i) {
                int r = wave * 16 + kg * 4 + i;
                float v = acc2[n][i] + bias;
                if (RELU_OUT) v = fmaxf(v, 0.f);
                sOut[r * N2 + c] = v;
            }
        }
        __syncthreads();
        float* out = (float*)outp;
        constexpr int CPR = N2 / 4;
        #pragma unroll
        for (int f = tid; f < 64 * CPR; f += 256) {
            int r = f / CPR, c = f - r * CPR;
            int gr = rowBlock + r;
            if (gr < n_nodes)
                *reinterpret_cast<float4*>(out + (size_t)gr * N2 + c * 4) =
                    *reinterpret_cast<const float4*>(sOut + r * N2 + c * 4);
        }
    }
}

extern "C" void kernel_launch(void* const* d_in, const int* in_sizes, int n_in,
                              void* d_out, int out_size, void* d_ws, size_t ws_size,
                              hipStream_t stream)
{
    const float* x   = (const float*)d_in[0];
    const int*   ei  = (const int*)d_in[1];
    const float* W1a = (const float*)d_in[2];
    const float* b1a = (const float*)d_in[3];
    const float* W1b = (const float*)d_in[4];
    const float* b1b = (const float*)d_in[5];
    const float* W2a = (const float*)d_in[6];
    const float* b2a = (const float*)d_in[7];
    const float* W2b = (const float*)d_in[8];
    const float* b2b = (const float*)d_in[9];

    const int n_nodes = in_sizes[0] / 64;
    const int n_edges = in_sizes[1] / 2;
    const int* src = ei;
    const int* dst = ei + n_edges;

    char* ws = (char*)d_ws;
    size_t o = 0;
    auto alloc = [&](size_t bytes) -> char* {
        char* p = ws + o;
        o += (bytes + 255) & ~(size_t)255;
        return p;
    };
    unsigned short* A    = (unsigned short*)alloc((size_t)n_nodes * 128 * 2);
    unsigned short* h    = (unsigned short*)alloc((size_t)n_nodes * 128 * 2);
    unsigned short* xb   = (unsigned short*)alloc((size_t)n_nodes * 64 * 2);
    int* eidx = (int*)alloc((size_t)n_edges * 4);
    int* cnt  = (int*)alloc((size_t)n_nodes * 4);
    int* offs = (int*)alloc((size_t)n_nodes * 4);
    int* cur  = (int*)alloc((size_t)n_nodes * 4);
    int* bsum = (int*)alloc(256 * 4);
    unsigned short* WT1a = (unsigned short*)alloc(64 * 128 * 2);
    unsigned short* WT1b = (unsigned short*)alloc(128 * 128 * 2);
    unsigned short* WT2a = (unsigned short*)alloc(128 * 128 * 2);
    unsigned short* WT2b = (unsigned short*)alloc(128 * 64 * 2);

    const int mlp_grid = (n_nodes + 63) / 64;
    const int segN = (n_nodes + NSEG - 1) / NSEG;
    const int seg_grid = NSEG * 128;    // 8 segments x 128 edge-chunks

    // ---- prep ----
    cvt_bf16_k<<<(n_nodes * 8 + 255) / 256, 256, 0, stream>>>(x, xb, n_nodes * 8);
    wt_prep_all_k<<<192, 256, 0, stream>>>(W1a, W1b, W2a, W2b, WT1a, WT1b, WT2a, WT2b);

    // ---- CSR build (XCD-segmented) ----
    hipMemsetAsync(cnt, 0, (size_t)n_nodes * sizeof(int), stream);
    hist_seg_k<<<seg_grid, 256, 0, stream>>>(dst, cnt, n_edges, segN);
    const int nb = (n_nodes + 2047) / 2048;
    scan_block_k<<<nb, 256, 0, stream>>>(cnt, offs, bsum, n_nodes);
    scan_bsum_k<<<1, 256, 0, stream>>>(bsum, nb);
    scan_add_k<<<nb, 256, 0, stream>>>(offs, cur, bsum, n_nodes);
    fill_seg_k<<<seg_grid, 256, 0, stream>>>(src, dst, cur, eidx, n_edges, segN);

    // ---- layer 1 ----
    gather_agg_k<64><<<(n_nodes + 31) / 32, 256, 0, stream>>>(
        xb, offs, cnt, eidx, A, n_nodes);
    mlp_mfma_k<64, 128, true, true><<<mlp_grid, 256, 0, stream>>>(
        A, WT1a, b1a, WT1b, b1b, h, n_nodes);

    // ---- layer 2 ----
    gather_agg_k<128><<<(n_nodes + 15) / 16, 256, 0, stream>>>(
        h, offs, cnt, eidx, A, n_nodes);
    mlp_mfma_k<128, 64, false, false><<<mlp_grid, 256, 0, stream>>>(
        A, WT2a, b2a, WT2b, b2b, d_out, n_nodes);
}